// Round 4
// baseline (197.665 us; speedup 1.0000x reference)
//
#include <hip/hip_runtime.h>
#include <math.h>

#define DD 4096
#define EE 64
#define NTOK 8192
#define BM 128           // tokens per block
#define KC 32            // K-chunk staged in LDS
#define BMP 132          // xs row stride (words): 16B-aligned, 132%32=4
#define EEP 68           // wsh row stride
#define NMB (NTOK / BM)  // 64 m-blocks
#define TAU 1e-3f        // near-tie flag threshold (f32 err worst-case ~2.5e-4)

// ---------------------------------------------------------------------------
// gemm (f32): block = 128 tok x 64 exp x kslen. 256 thr, tile 4 tok x 8 exp.
// LDS k-major, padded strides; reg-prefetch, single buffer, 2 barriers/chunk.
// Partials (f32, deterministic order) -> ws part[ks][token][e].
// ---------------------------------------------------------------------------
__global__ __launch_bounds__(256, 4) void moirai_gemm(
        const float* __restrict__ x, const float* __restrict__ W,
        float* __restrict__ part, int kslen) {
    __shared__ float xs[KC][BMP];    // 16.9 KB
    __shared__ float wsh[KC][EEP];   //  8.7 KB

    const int t    = threadIdx.x;
    const int tx   = t >> 5;         // 0..7  expert group (e = tx*8+ee)
    const int ty   = t & 31;         // 0..31 token group  (m = ty*4+mm)
    const int mblk = blockIdx.x & (NMB - 1);
    const int ks   = blockIdx.x >> 6;        // grid = NMB * KS
    const int m0   = mblk * BM;
    const int k0   = ks * kslen;

    const int r  = t >> 3;           // 0..31 staging row base
    const int sg = t & 7;            // 16B segment within 32-f32 row

    float acc[4][8];
#pragma unroll
    for (int mm = 0; mm < 4; mm++)
#pragma unroll
        for (int ee = 0; ee < 8; ee++) acc[mm][ee] = 0.0f;

    const int nch = kslen / KC;
    float4 xr[4], wr[2];

    auto load_regs = [&](int c) {
        const int kb = k0 + c * KC + sg * 4;
#pragma unroll
        for (int i = 0; i < 4; i++)
            xr[i] = *(const float4*)(x + (size_t)(m0 + r + i * 32) * DD + kb);
#pragma unroll
        for (int i = 0; i < 2; i++)
            wr[i] = *(const float4*)(W + (size_t)(r + i * 32) * DD + kb);
    };
    auto store_lds = [&]() {
#pragma unroll
        for (int i = 0; i < 4; i++) {
            const int rr = r + i * 32;
            xs[sg * 4 + 0][rr] = xr[i].x; xs[sg * 4 + 1][rr] = xr[i].y;
            xs[sg * 4 + 2][rr] = xr[i].z; xs[sg * 4 + 3][rr] = xr[i].w;
        }
#pragma unroll
        for (int i = 0; i < 2; i++) {
            const int ee = r + i * 32;
            wsh[sg * 4 + 0][ee] = wr[i].x; wsh[sg * 4 + 1][ee] = wr[i].y;
            wsh[sg * 4 + 2][ee] = wr[i].z; wsh[sg * 4 + 3][ee] = wr[i].w;
        }
    };

    load_regs(0);
    store_lds();
    __syncthreads();

    for (int c = 0; c < nch; c++) {
        if (c + 1 < nch) load_regs(c + 1);   // prefetch hides HBM latency

#pragma unroll 4
        for (int k = 0; k < KC; k++) {
            const float4 xa = *(const float4*)&xs[k][ty * 4];
            const float4 wa = *(const float4*)&wsh[k][tx * 8];
            const float4 wb = *(const float4*)&wsh[k][tx * 8 + 4];
            const float xv[4] = {xa.x, xa.y, xa.z, xa.w};
            const float wv[8] = {wa.x, wa.y, wa.z, wa.w, wb.x, wb.y, wb.z, wb.w};
#pragma unroll
            for (int mm = 0; mm < 4; mm++)
#pragma unroll
                for (int ee = 0; ee < 8; ee++)
                    acc[mm][ee] = fmaf(xv[mm], wv[ee], acc[mm][ee]);
        }

        if (c + 1 < nch) {
            __syncthreads();     // all reads of current chunk done
            store_lds();
            __syncthreads();     // staging visible
        }
    }

#pragma unroll
    for (int mm = 0; mm < 4; mm++) {
        float* po = part + ((size_t)ks * NTOK + (m0 + ty * 4 + mm)) * EE + tx * 8;
        float4 o1 = {acc[mm][0], acc[mm][1], acc[mm][2], acc[mm][3]};
        float4 o2 = {acc[mm][4], acc[mm][5], acc[mm][6], acc[mm][7]};
        *(float4*)(po)     = o1;
        *(float4*)(po + 4) = o2;
    }
}

// ---------------------------------------------------------------------------
// topk: wave per token, lane = expert. f32 sum of KS partials + bias ->
// top-2 + third-max. If any gap < TAU, recompute the row exactly in f64
// (lane = expert, validated round-1 semantics) and redo selection.
// Output: [gate_probs 16384 f32][indices-as-f32 16384].
// ---------------------------------------------------------------------------
__global__ void moirai_topk(const float* __restrict__ part,
                            const float* __restrict__ bias,
                            const float* __restrict__ x,
                            const float* __restrict__ W,
                            float* __restrict__ out, int KS) {
    const int lane  = threadIdx.x & 63;
    const int token = blockIdx.x * 4 + (threadIdx.x >> 6);

    float v = bias[lane];
    for (int ks = 0; ks < KS; ks++)
        v += part[((size_t)ks * NTOK + token) * EE + lane];

    // f32 top-2 butterfly with jax tie-break (lower index wins ties)
    float v1 = v, v2 = -3.4e38f;
    int   i1 = lane, i2 = 127;
#pragma unroll
    for (int off = 1; off < 64; off <<= 1) {
        float u1 = __shfl_xor(v1, off);
        float u2 = __shfl_xor(v2, off);
        int   j1 = __shfl_xor(i1, off);
        int   j2 = __shfl_xor(i2, off);
        bool u1_beats_v1 = (u1 > v1) || (u1 == v1 && j1 < i1);
        if (u1_beats_v1) {
            bool v1_beats_u2 = (v1 > u2) || (v1 == u2 && i1 < j2);
            if (v1_beats_u2) { v2 = v1; i2 = i1; }
            else             { v2 = u2; i2 = j2; }
            v1 = u1; i1 = j1;
        } else {
            bool u1_beats_v2 = (u1 > v2) || (u1 == v2 && j1 < i2);
            if (u1_beats_v2) { v2 = u1; i2 = j1; }
        }
    }

    // third-largest value (exclude top-2 by index)
    float ve = (lane == i1 || lane == i2) ? -3.4e38f : v;
#pragma unroll
    for (int off = 1; off < 64; off <<= 1)
        ve = fmaxf(ve, __shfl_xor(ve, off));

    double d1 = (double)v1, d2 = (double)v2;
    int    o1 = i1, o2 = i2;

    if ((v1 - v2 < TAU) || (v2 - ve < TAU)) {
        // exact f64 recompute of this row (wave-uniform branch)
        const float* xr = x + (size_t)token * DD;
        const float* wr = W + (size_t)lane * DD;
        double a0 = 0.0, a1 = 0.0, a2 = 0.0, a3 = 0.0;
        for (int k = 0; k < DD; k += 4) {
            const float4 xv = *(const float4*)(xr + k);   // uniform: broadcast
            const float4 wv = *(const float4*)(wr + k);
            a0 += (double)xv.x * (double)wv.x;
            a1 += (double)xv.y * (double)wv.y;
            a2 += (double)xv.z * (double)wv.z;
            a3 += (double)xv.w * (double)wv.w;
        }
        double vd = ((a0 + a1) + (a2 + a3)) + (double)bias[lane];

        double e1 = vd, e2 = -1.0e300;
        int    f1 = lane, f2 = 127;
#pragma unroll
        for (int off = 1; off < 64; off <<= 1) {
            double u1 = __shfl_xor(e1, off);
            double u2 = __shfl_xor(e2, off);
            int    j1 = __shfl_xor(f1, off);
            int    j2 = __shfl_xor(f2, off);
            bool u1_beats_e1 = (u1 > e1) || (u1 == e1 && j1 < f1);
            if (u1_beats_e1) {
                bool e1_beats_u2 = (e1 > u2) || (e1 == u2 && f1 < j2);
                if (e1_beats_u2) { e2 = e1; f2 = f1; }
                else             { e2 = u2; f2 = j2; }
                e1 = u1; f1 = j1;
            } else {
                bool u1_beats_e2 = (u1 > e2) || (u1 == e2 && j1 < f2);
                if (u1_beats_e2) { e2 = u1; f2 = j1; }
            }
        }
        d1 = e1; d2 = e2; o1 = f1; o2 = f2;
    }

    if (lane == 0) {
        double ex = exp(d2 - d1);    // d1 >= d2 -> stable
        double s  = 1.0 + ex;
        out[token * 2 + 0] = (float)(1.0 / s);
        out[token * 2 + 1] = (float)(ex / s);
        out[NTOK * 2 + token * 2 + 0] = (float)o1;
        out[NTOK * 2 + token * 2 + 1] = (float)o2;
    }
}

// ---------------------------------------------------------------------------
extern "C" void kernel_launch(void* const* d_in, const int* in_sizes, int n_in,
                              void* d_out, int out_size, void* d_ws, size_t ws_size,
                              hipStream_t stream) {
    const float* x = (const float*)d_in[0];
    const float* W = (const float*)d_in[1];
    const float* b = (const float*)d_in[2];
    float* out = (float*)d_out;

    float* part = (float*)d_ws;

    int KS = 16;  // K-split; kslen stays a multiple of KC
    while (KS > 1 && (size_t)KS * NTOK * EE * 4 > ws_size) KS >>= 1;
    const int kslen = DD / KS;

    moirai_gemm<<<NMB * KS, 256, 0, stream>>>(x, W, part, kslen);
    moirai_topk<<<NTOK / 4, 256, 0, stream>>>(part, b, x, W, out, KS);
}

// Round 5
// 117.871 us; speedup vs baseline: 1.6770x; 1.6770x over previous
//
#include <hip/hip_runtime.h>
#include <math.h>

#define DD 4096
#define EE 64
#define NTOK 8192
#define BM 128           // tokens per block
#define KC 32            // K-chunk staged in LDS
#define BMP 132          // xs row stride (words): 16B-aligned, 132%32=4
#define EEP 68           // wsh row stride
#define NMB (NTOK / BM)  // 64 m-blocks
#define TAU 1e-3f        // near-tie flag threshold (f32 err worst-case ~1e-5)

// ---------------------------------------------------------------------------
// gemm (f32): block = 128 tok x 64 exp x kslen. 256 thr, tile 4 tok x 8 exp.
// LDS k-major, padded strides; reg-prefetch, single buffer, 2 barriers/chunk.
// Partials (f32, deterministic order) -> part[ks][token][e].
// Block 0 also zeroes the flagged-row counter (stream-ordered before topk).
// ---------------------------------------------------------------------------
__global__ __launch_bounds__(256, 4) void moirai_gemm(
        const float* __restrict__ x, const float* __restrict__ W,
        float* __restrict__ part, int* __restrict__ count, int kslen) {
    __shared__ float xs[KC][BMP];    // 16.9 KB
    __shared__ float wsh[KC][EEP];   //  8.7 KB

    const int t    = threadIdx.x;
    const int tx   = t >> 5;         // 0..7  expert group (e = tx*8+ee)
    const int ty   = t & 31;         // 0..31 token group  (m = ty*4+mm)
    const int mblk = blockIdx.x & (NMB - 1);
    const int ks   = blockIdx.x >> 6;        // grid = NMB * KS
    const int m0   = mblk * BM;
    const int k0   = ks * kslen;

    if (blockIdx.x == 0 && t == 0) *count = 0;

    const int r  = t >> 3;           // 0..31 staging row base
    const int sg = t & 7;            // 16B segment within 32-f32 row

    float acc[4][8];
#pragma unroll
    for (int mm = 0; mm < 4; mm++)
#pragma unroll
        for (int ee = 0; ee < 8; ee++) acc[mm][ee] = 0.0f;

    const int nch = kslen / KC;
    float4 xr[4], wr[2];

    auto load_regs = [&](int c) {
        const int kb = k0 + c * KC + sg * 4;
#pragma unroll
        for (int i = 0; i < 4; i++)
            xr[i] = *(const float4*)(x + (size_t)(m0 + r + i * 32) * DD + kb);
#pragma unroll
        for (int i = 0; i < 2; i++)
            wr[i] = *(const float4*)(W + (size_t)(r + i * 32) * DD + kb);
    };
    auto store_lds = [&]() {
#pragma unroll
        for (int i = 0; i < 4; i++) {
            const int rr = r + i * 32;
            xs[sg * 4 + 0][rr] = xr[i].x; xs[sg * 4 + 1][rr] = xr[i].y;
            xs[sg * 4 + 2][rr] = xr[i].z; xs[sg * 4 + 3][rr] = xr[i].w;
        }
#pragma unroll
        for (int i = 0; i < 2; i++) {
            const int ee = r + i * 32;
            wsh[sg * 4 + 0][ee] = wr[i].x; wsh[sg * 4 + 1][ee] = wr[i].y;
            wsh[sg * 4 + 2][ee] = wr[i].z; wsh[sg * 4 + 3][ee] = wr[i].w;
        }
    };

    load_regs(0);
    store_lds();
    __syncthreads();

    for (int c = 0; c < nch; c++) {
        if (c + 1 < nch) load_regs(c + 1);   // prefetch hides HBM latency

#pragma unroll 4
        for (int k = 0; k < KC; k++) {
            const float4 xa = *(const float4*)&xs[k][ty * 4];
            const float4 wa = *(const float4*)&wsh[k][tx * 8];
            const float4 wb = *(const float4*)&wsh[k][tx * 8 + 4];
            const float xv[4] = {xa.x, xa.y, xa.z, xa.w};
            const float wv[8] = {wa.x, wa.y, wa.z, wa.w, wb.x, wb.y, wb.z, wb.w};
#pragma unroll
            for (int mm = 0; mm < 4; mm++)
#pragma unroll
                for (int ee = 0; ee < 8; ee++)
                    acc[mm][ee] = fmaf(xv[mm], wv[ee], acc[mm][ee]);
        }

        if (c + 1 < nch) {
            __syncthreads();     // all reads of current chunk done
            store_lds();
            __syncthreads();     // staging visible
        }
    }

#pragma unroll
    for (int mm = 0; mm < 4; mm++) {
        float* po = part + ((size_t)ks * NTOK + (m0 + ty * 4 + mm)) * EE + tx * 8;
        float4 o1 = {acc[mm][0], acc[mm][1], acc[mm][2], acc[mm][3]};
        float4 o2 = {acc[mm][4], acc[mm][5], acc[mm][6], acc[mm][7]};
        *(float4*)(po)     = o1;
        *(float4*)(po + 4) = o2;
    }
}

// ---------------------------------------------------------------------------
// topk pass 1: wave per token, lane = expert. f32 sum of KS partials + bias
// -> top-2 + third-max. Near-tie rows appended to flagged list (fix kernel
// overwrites them). Output: [gate_probs 16384 f32][indices-as-f32 16384].
// ---------------------------------------------------------------------------
__global__ void moirai_topk(const float* __restrict__ part,
                            const float* __restrict__ bias,
                            float* __restrict__ out,
                            int* __restrict__ count, int* __restrict__ list,
                            int KS) {
    const int lane  = threadIdx.x & 63;
    const int token = blockIdx.x * 4 + (threadIdx.x >> 6);

    float v = bias[lane];
    for (int ks = 0; ks < KS; ks++)
        v += part[((size_t)ks * NTOK + token) * EE + lane];

    // f32 top-2 butterfly with jax tie-break (lower index wins ties)
    float v1 = v, v2 = -3.4e38f;
    int   i1 = lane, i2 = 127;
#pragma unroll
    for (int off = 1; off < 64; off <<= 1) {
        float u1 = __shfl_xor(v1, off);
        float u2 = __shfl_xor(v2, off);
        int   j1 = __shfl_xor(i1, off);
        int   j2 = __shfl_xor(i2, off);
        bool u1_beats_v1 = (u1 > v1) || (u1 == v1 && j1 < i1);
        if (u1_beats_v1) {
            bool v1_beats_u2 = (v1 > u2) || (v1 == u2 && i1 < j2);
            if (v1_beats_u2) { v2 = v1; i2 = i1; }
            else             { v2 = u2; i2 = j2; }
            v1 = u1; i1 = j1;
        } else {
            bool u1_beats_v2 = (u1 > v2) || (u1 == v2 && j1 < i2);
            if (u1_beats_v2) { v2 = u1; i2 = j1; }
        }
    }

    // third-largest value (exclude top-2 by index)
    float ve = (lane == i1 || lane == i2) ? -3.4e38f : v;
#pragma unroll
    for (int off = 1; off < 64; off <<= 1)
        ve = fmaxf(ve, __shfl_xor(ve, off));

    if (lane == 0) {
        if ((v1 - v2 < TAU) || (v2 - ve < TAU)) {
            int pos = atomicAdd(count, 1);
            list[pos] = token;
        }
        double ex = exp((double)v2 - (double)v1);   // v1 >= v2 -> stable
        double s  = 1.0 + ex;
        out[token * 2 + 0] = (float)(1.0 / s);
        out[token * 2 + 1] = (float)(ex / s);
        out[NTOK * 2 + token * 2 + 0] = (float)i1;
        out[NTOK * 2 + token * 2 + 1] = (float)i2;
    }
}

// ---------------------------------------------------------------------------
// fix: exact f64 recompute of flagged rows, one block per row (grid-stride).
// thread t: expert t&63, k-slice t>>6 (4 x 1024). LDS reduce -> wave 0 does
// f64 top-2 (validated tie-break) and overwrites the row's outputs.
// ---------------------------------------------------------------------------
__global__ __launch_bounds__(256) void moirai_fix(
        const float* __restrict__ x, const float* __restrict__ W,
        const float* __restrict__ bias,
        const int* __restrict__ count, const int* __restrict__ list,
        float* __restrict__ out) {
    __shared__ double red[4][EE];

    const int t = threadIdx.x;
    const int e = t & 63;
    const int q = t >> 6;
    const int n = *count;

    for (int idx = blockIdx.x; idx < n; idx += gridDim.x) {
        const int token = list[idx];
        const float* xr = x + (size_t)token * DD + q * (DD / 4);
        const float* wr = W + (size_t)e * DD + q * (DD / 4);

        double a0 = 0.0, a1 = 0.0, a2 = 0.0, a3 = 0.0;
#pragma unroll 4
        for (int k = 0; k < DD / 4; k += 4) {
            const float4 xv = *(const float4*)(xr + k);
            const float4 wv = *(const float4*)(wr + k);
            a0 += (double)xv.x * (double)wv.x;
            a1 += (double)xv.y * (double)wv.y;
            a2 += (double)xv.z * (double)wv.z;
            a3 += (double)xv.w * (double)wv.w;
        }
        red[q][e] = (a0 + a1) + (a2 + a3);
        __syncthreads();

        if (q == 0) {
            double vd = ((red[0][e] + red[1][e]) + (red[2][e] + red[3][e]))
                        + (double)bias[e];

            double e1 = vd, e2 = -1.0e300;
            int    f1 = e,  f2 = 127;
#pragma unroll
            for (int off = 1; off < 64; off <<= 1) {
                double u1 = __shfl_xor(e1, off);
                double u2 = __shfl_xor(e2, off);
                int    j1 = __shfl_xor(f1, off);
                int    j2 = __shfl_xor(f2, off);
                bool u1_beats_e1 = (u1 > e1) || (u1 == e1 && j1 < f1);
                if (u1_beats_e1) {
                    bool e1_beats_u2 = (e1 > u2) || (e1 == u2 && f1 < j2);
                    if (e1_beats_u2) { e2 = e1; f2 = f1; }
                    else             { e2 = u2; f2 = j2; }
                    e1 = u1; f1 = j1;
                } else {
                    bool u1_beats_e2 = (u1 > e2) || (u1 == e2 && j1 < f2);
                    if (u1_beats_e2) { e2 = u1; f2 = j1; }
                }
            }

            if (e == 0) {
                double ex = exp(e2 - e1);
                double s  = 1.0 + ex;
                out[token * 2 + 0] = (float)(1.0 / s);
                out[token * 2 + 1] = (float)(ex / s);
                out[NTOK * 2 + token * 2 + 0] = (float)f1;
                out[NTOK * 2 + token * 2 + 1] = (float)f2;
            }
        }
        __syncthreads();   // LDS reuse guard for next grid-stride iteration
    }
}

// ---------------------------------------------------------------------------
extern "C" void kernel_launch(void* const* d_in, const int* in_sizes, int n_in,
                              void* d_out, int out_size, void* d_ws, size_t ws_size,
                              hipStream_t stream) {
    const float* x = (const float*)d_in[0];
    const float* W = (const float*)d_in[1];
    const float* b = (const float*)d_in[2];
    float* out = (float*)d_out;

    // ws layout: [count 4B | list NTOK*4B] padded to 64 KB, then partials
    const size_t HDR = 65536;
    int*   count = (int*)d_ws;
    int*   list  = (int*)d_ws + 1;
    float* part  = (float*)((char*)d_ws + HDR);

    int KS = 16;  // K-split; kslen stays a multiple of KC
    while (KS > 1 && HDR + (size_t)KS * NTOK * EE * 4 > ws_size) KS >>= 1;
    const int kslen = DD / KS;

    moirai_gemm<<<NMB * KS, 256, 0, stream>>>(x, W, part, count, kslen);
    moirai_topk<<<NTOK / 4, 256, 0, stream>>>(part, b, out, count, list, KS);
    moirai_fix<<<256, 256, 0, stream>>>(x, W, b, count, list, out);
}